// Round 1
// 256.671 us; speedup vs baseline: 1.0594x; 1.0594x over previous
//
#include <hip/hip_runtime.h>
#include <math.h>
#include <stdint.h>

constexpr int LL = 16384;
constexpr int NROW = 65536;          // N*L
constexpr int NPAIR = NROW * 8;      // 524288 (row,head) pairs
constexpr float EPS = 1e-6f;
constexpr float LN_EPS = 1e-5f;

// ws float offsets — all stat arrays are atomically accumulated (zeroed by k_zero)
constexpr int OFF_QSUM = 0;      // [4][128]  sum_l sig(q)
constexpr int OFF_KSUM = 512;    // [4][128]  sum_s sig(k)
constexpr int OFF_QN   = 1024;   // [4][128]  sum_l q*nr
constexpr int OFF_KN   = 1536;   // [4][128]  sum_s k*nc
constexpr int OFF_SSUM = 2048;   // [4][8]    sum_s exp(ncr)
constexpr int OFF_KVU  = 2080;   // [4][8][256] unscaled weighted KV
constexpr int STATS_FLOATS = OFF_KVU + 4 * 2048;  // 10272
constexpr int FLOAT_END = 10304;                  // pad to 256-multiple
constexpr size_t MIR_Q_BYTE = (size_t)FLOAT_END * 4;
constexpr size_t MIR_ELEMS  = (size_t)NPAIR * 16;
constexpr size_t MIR_K_BYTE = MIR_Q_BYTE + MIR_ELEMS * 2;
constexpr size_t WS_FULL    = MIR_K_BYTE + MIR_ELEMS * 2;   // ~33.6 MB

__device__ __forceinline__ float sigm(float x) { return __fdividef(1.f, 1.f + __expf(-x)); }
__device__ __forceinline__ unsigned short f2bf(float f) {
  uint32_t x = __float_as_uint(f);
  return (unsigned short)((x + 0x7FFFu + ((x >> 16) & 1u)) >> 16);
}
__device__ __forceinline__ float bf2f(unsigned short u) {
  return __uint_as_float(((uint32_t)u) << 16);
}

template <bool MIR>
__device__ __forceinline__ void load_sig(const unsigned short* mir, const float* fp, int p, float* r) {
  if (MIR) {
    const uint4* p4 = reinterpret_cast<const uint4*>(mir + (size_t)p * 16);
    uint4 a = p4[0], b = p4[1];
    uint32_t w[8] = {a.x, a.y, a.z, a.w, b.x, b.y, b.z, b.w};
#pragma unroll
    for (int j = 0; j < 8; ++j) {
      r[2 * j]     = bf2f((unsigned short)(w[j] & 0xFFFFu));
      r[2 * j + 1] = bf2f((unsigned short)(w[j] >> 16));
    }
  } else {
    const float4* p4 = reinterpret_cast<const float4*>(fp + (size_t)p * 16);
#pragma unroll
    for (int j = 0; j < 4; ++j) {
      float4 a = p4[j];
      r[4 * j] = sigm(a.x); r[4 * j + 1] = sigm(a.y);
      r[4 * j + 2] = sigm(a.z); r[4 * j + 3] = sigm(a.w);
    }
  }
}
__device__ __forceinline__ void load_raw16(const float* fp, int p, float* r) {
  const float4* p4 = reinterpret_cast<const float4*>(fp + (size_t)p * 16);
#pragma unroll
  for (int j = 0; j < 4; ++j) {
    float4 a = p4[j];
    r[4 * j] = a.x; r[4 * j + 1] = a.y; r[4 * j + 2] = a.z; r[4 * j + 3] = a.w;
  }
}

// sums over the 8 lanes sharing (lane&7); every lane gets its group's sum
__device__ __forceinline__ float hred(float v) {
  v += __shfl_xor(v, 8, 64);
  v += __shfl_xor(v, 16, 64);
  v += __shfl_xor(v, 32, 64);
  return v;
}

// block-reduce 32 per-thread (h,d)-values, then one atomicAdd per thread into
// the global stat arrays (q side and k side).
__device__ __forceinline__ void stat_atomic2(float* q, float* k, float* dQ, float* dK, int tid) {
  __shared__ float w4[4][256];
  const int wave = tid >> 6, lane = tid & 63;
#pragma unroll
  for (int d = 0; d < 16; ++d) { q[d] = hred(q[d]); k[d] = hred(k[d]); }
  if (lane < 8) {
#pragma unroll
    for (int d = 0; d < 16; ++d) {
      w4[wave][lane * 16 + d] = q[d];
      w4[wave][128 + lane * 16 + d] = k[d];
    }
  }
  __syncthreads();
  const float v = w4[0][tid] + w4[1][tid] + w4[2][tid] + w4[3][tid];
  if (tid < 128) atomicAdd(dQ + tid, v);
  else atomicAdd(dK + (tid - 128), v);
}

// q-side-only variant (16 values per thread)
__device__ __forceinline__ void stat_atomic1(float* q, float* dQ, int tid) {
  __shared__ float w1[4][128];
  const int wave = tid >> 6, lane = tid & 63;
#pragma unroll
  for (int d = 0; d < 16; ++d) q[d] = hred(q[d]);
  if (lane < 8) {
#pragma unroll
    for (int d = 0; d < 16; ++d) w1[wave][lane * 16 + d] = q[d];
  }
  __syncthreads();
  if (tid < 128) atomicAdd(dQ + tid, w1[0][tid] + w1[1][tid] + w1[2][tid] + w1[3][tid]);
}

// zero the atomic accumulators (STATS_FLOATS is a multiple of 4)
__global__ __launch_bounds__(256) void k_zero(float4* ws4) {
  const int i = blockIdx.x * 256 + threadIdx.x;
  if (i < STATS_FLOATS / 4) ws4[i] = make_float4(0.f, 0.f, 0.f, 0.f);
}

// Pass 1: sigmoid, bf16 mirrors, qsum/ksum via block-reduce + atomicAdd
template <bool MIR>
__global__ __launch_bounds__(256) void k_prep(const float* __restrict__ Q, const float* __restrict__ K,
                                              float* __restrict__ ws,
                                              unsigned short* __restrict__ sQ, unsigned short* __restrict__ sK) {
  const int tid = threadIdx.x;
  const int p = blockIdx.x * 256 + tid;
  const int n = blockIdx.x >> 9;
  float q[16], k[16];
  load_sig<false>(nullptr, Q, p, q);
  load_sig<false>(nullptr, K, p, k);
  if (MIR) {
    union U { unsigned short u[8]; uint4 v; };
    U a, b;
#pragma unroll
    for (int j = 0; j < 8; ++j) { a.u[j] = f2bf(q[j]); b.u[j] = f2bf(q[8 + j]); }
    uint4* dq = reinterpret_cast<uint4*>(sQ + (size_t)p * 16);
    dq[0] = a.v; dq[1] = b.v;
#pragma unroll
    for (int j = 0; j < 8; ++j) { a.u[j] = f2bf(k[j]); b.u[j] = f2bf(k[8 + j]); }
    uint4* dk = reinterpret_cast<uint4*>(sK + (size_t)p * 16);
    dk[0] = a.v; dk[1] = b.v;
  }
  stat_atomic2(q, k, ws + OFF_QSUM + n * 128, ws + OFF_KSUM + n * 128, tid);
}

// Pass 2: q-side refine only — qn = sum_l q*nr (k-side moved into k_kv)
template <bool MIR>
__global__ __launch_bounds__(256) void k_refq(const float* __restrict__ Q,
                                              const unsigned short* __restrict__ sQ,
                                              float* __restrict__ ws) {
  const int tid = threadIdx.x;
  const int p = blockIdx.x * 256 + tid;
  const int n = blockIdx.x >> 9;
  __shared__ float ksE[128];
  if (tid < 128) ksE[tid] = ws[OFF_KSUM + n * 128 + tid] + EPS;
  __syncthreads();
  float q[16];
  load_sig<MIR>(sQ, Q, p, q);
  const int h = tid & 7;
  float dr = 0.f;
#pragma unroll
  for (int d = 0; d < 16; ++d) dr += (q[d] + EPS) * ksE[h * 16 + d];
  const float nr = __fdividef(1.f, dr);
#pragma unroll
  for (int d = 0; d < 16; ++d) q[d] *= nr;
  stat_atomic1(q, ws + OFF_QN + n * 128, tid);
}

// Pass 3 (fused): per k-row compute nc (kn partial), refine weight w = exp(k.qnE),
// ssum partial, and weighted-KV tile; all accumulated via atomics.
template <bool MIR>
__global__ __launch_bounds__(256) void k_kv(const float* __restrict__ K, const float* __restrict__ V,
                                            const unsigned short* __restrict__ sK,
                                            float* __restrict__ ws) {
  const int tid = threadIdx.x;
  const int blk = blockIdx.x;      // 1024 blocks × 64 rows
  const int n = blk >> 8;
  constexpr int RS = 132;          // row stride: head-stride 16 (aligned wide reads), +4 pad
  __shared__ float qnE[128], qsE[128];
  __shared__ float ssb[8];
  __shared__ __align__(16) float kwL[32 * RS];
  __shared__ __align__(16) float vL[32 * RS];
  if (tid < 128) {
    qnE[tid] = ws[OFF_QN + n * 128 + tid] + EPS;
    qsE[tid] = ws[OFF_QSUM + n * 128 + tid] + EPS;
  }
  if (tid < 8) ssb[tid] = 0.f;
  __syncthreads();
  const int h = tid & 7, ri = tid >> 3, lane = tid & 63;
  const int h2 = tid >> 5;
  const int d0 = ((tid >> 2) & 7) * 2;
  const int e0 = (tid & 3) * 4;
  float acc[2][4] = {{0.f, 0.f, 0.f, 0.f}, {0.f, 0.f, 0.f, 0.f}};
  float kn[16];
#pragma unroll
  for (int d = 0; d < 16; ++d) kn[d] = 0.f;
  for (int t = 0; t < 2; ++t) {
    const int p = (blk * 64 + t * 32) * 8 + tid;
    float k[16], v[16];
    load_sig<MIR>(sK, K, p, k);
    load_raw16(V, p, v);
    float dc = 0.f, ncr = 0.f;
#pragma unroll
    for (int d = 0; d < 16; ++d) {
      const float ke = k[d] + EPS;
      dc += ke * qsE[h * 16 + d];
      ncr += ke * qnE[h * 16 + d];
    }
    const float nc = __fdividef(1.f, dc);
#pragma unroll
    for (int d = 0; d < 16; ++d) kn[d] += k[d] * nc;
    const float w = __expf(ncr);   // ncr is O(1): no max-subtraction needed
    float sw = hred(w);
    if (lane < 8) atomicAdd(&ssb[lane], sw);
    const int wb = ri * RS + h * 16;
#pragma unroll
    for (int d = 0; d < 16; ++d) { kwL[wb + d] = k[d] * w; vL[wb + d] = v[d]; }
    __syncthreads();
    const int rb0 = h2 * 16;
#pragma unroll 4
    for (int r = 0; r < 32; ++r) {
      const int rb = r * RS + rb0;
      const float2 kk = *reinterpret_cast<const float2*>(&kwL[rb + d0]);
      const float4 vv = *reinterpret_cast<const float4*>(&vL[rb + e0]);
      acc[0][0] += kk.x * vv.x; acc[0][1] += kk.x * vv.y;
      acc[0][2] += kk.x * vv.z; acc[0][3] += kk.x * vv.w;
      acc[1][0] += kk.y * vv.x; acc[1][1] += kk.y * vv.y;
      acc[1][2] += kk.y * vv.z; acc[1][3] += kk.y * vv.w;
    }
    __syncthreads();
  }
  // kn block-reduce + atomic
  stat_atomic1(kn, ws + OFF_KN + n * 128, tid);
  if (tid < 8) atomicAdd(&ws[OFF_SSUM + n * 8 + tid], ssb[tid]);
  // KV tile atomic accumulate: 8 adds/thread, 256 contributing blocks per address
  float* kv = ws + OFF_KVU + n * 2048 + h2 * 256;
#pragma unroll
  for (int j = 0; j < 4; ++j) atomicAdd(&kv[d0 * 16 + e0 + j], acc[0][j]);
#pragma unroll
  for (int j = 0; j < 4; ++j) atomicAdd(&kv[(d0 + 1) * 16 + e0 + j], acc[1][j]);
}

// Pass 4: x = q@kv * nr * nrr + v, LayerNorm, write out.
// Softmax scale L/ssum is applied while staging KV into LDS.
template <bool MIR>
__global__ __launch_bounds__(256) void k_out(const float* __restrict__ Q, const float* __restrict__ V,
                                             const unsigned short* __restrict__ sQ,
                                             const float* __restrict__ gamma, const float* __restrict__ beta,
                                             const float* __restrict__ ws, float* __restrict__ out) {
  const int tid = threadIdx.x;
  const int p = blockIdx.x * 256 + tid;
  const int n = blockIdx.x >> 9;
  __shared__ __align__(16) float kvs[8 * 260];  // pad 260 → conflict-free by h
  __shared__ float ksE[128], knE[128], gm[16], bt[16], ssE[8];
  if (tid < 8) ssE[tid] = __fdividef((float)LL, ws[OFF_SSUM + n * 8 + tid]);
  if (tid >= 8 && tid < 136) {
    const int i = tid - 8;
    ksE[i] = ws[OFF_KSUM + n * 128 + i] + EPS;
    knE[i] = ws[OFF_KN + n * 128 + i] + EPS;
  }
  if (tid >= 136 && tid < 152) gm[tid - 136] = gamma[tid - 136];
  else if (tid >= 152 && tid < 168) bt[tid - 152] = beta[tid - 152];
  __syncthreads();
  for (int i = tid; i < 2048; i += 256) {
    const int hh = i >> 8, de = i & 255;
    kvs[hh * 260 + de] = ws[OFF_KVU + n * 2048 + i] * ssE[hh];
  }
  __syncthreads();
  const int h = tid & 7;
  float q[16], v[16];
  load_sig<MIR>(sQ, Q, p, q);
  load_raw16(V, p, v);
  float dr = 0.f, drr = 0.f;
#pragma unroll
  for (int d = 0; d < 16; ++d) {
    const float qe = q[d] + EPS;
    dr += qe * ksE[h * 16 + d];
    drr += qe * knE[h * 16 + d];
  }
  const float sc = __fdividef(1.f, dr) * sigm(drr);
  float x[16];
#pragma unroll
  for (int e = 0; e < 16; ++e) x[e] = 0.f;
#pragma unroll
  for (int d = 0; d < 16; ++d) {
    const float qd = q[d];
    const float4* kr = reinterpret_cast<const float4*>(&kvs[h * 260 + d * 16]);
#pragma unroll
    for (int j = 0; j < 4; ++j) {
      float4 a = kr[j];
      x[4 * j] += qd * a.x; x[4 * j + 1] += qd * a.y;
      x[4 * j + 2] += qd * a.z; x[4 * j + 3] += qd * a.w;
    }
  }
#pragma unroll
  for (int e = 0; e < 16; ++e) x[e] = x[e] * sc + v[e];
  float mean = 0.f;
#pragma unroll
  for (int e = 0; e < 16; ++e) mean += x[e];
  mean *= (1.f / 16.f);
  float var = 0.f;
#pragma unroll
  for (int e = 0; e < 16; ++e) { const float t = x[e] - mean; var += t * t; }
  var *= (1.f / 16.f);
  const float inv = rsqrtf(var + LN_EPS);
#pragma unroll
  for (int e = 0; e < 16; ++e) x[e] = (x[e] - mean) * inv * gm[e] + bt[e];
  float4* op = reinterpret_cast<float4*>(out + (size_t)p * 16);
  op[0] = make_float4(x[0], x[1], x[2], x[3]);
  op[1] = make_float4(x[4], x[5], x[6], x[7]);
  op[2] = make_float4(x[8], x[9], x[10], x[11]);
  op[3] = make_float4(x[12], x[13], x[14], x[15]);
}

extern "C" void kernel_launch(void* const* d_in, const int* in_sizes, int n_in,
                              void* d_out, int out_size, void* d_ws, size_t ws_size,
                              hipStream_t stream) {
  const float* Q = (const float*)d_in[0];
  const float* K = (const float*)d_in[1];
  const float* V = (const float*)d_in[2];
  const float* gamma = (const float*)d_in[3];
  const float* beta = (const float*)d_in[4];
  float* ws = (float*)d_ws;
  float* out = (float*)d_out;
  unsigned short* sQ = (unsigned short*)((char*)d_ws + MIR_Q_BYTE);
  unsigned short* sK = (unsigned short*)((char*)d_ws + MIR_K_BYTE);

  const dim3 blk(256);
  const int gPair = NPAIR / 256;  // 2048
  const int gKv = NROW / 64;      // 1024
  const int gZero = (STATS_FLOATS / 4 + 255) / 256;  // 11

  k_zero<<<gZero, blk, 0, stream>>>(reinterpret_cast<float4*>(ws));
  if (ws_size >= WS_FULL) {
    k_prep<true><<<gPair, blk, 0, stream>>>(Q, K, ws, sQ, sK);
    k_refq<true><<<gPair, blk, 0, stream>>>(Q, sQ, ws);
    k_kv<true><<<gKv, blk, 0, stream>>>(K, V, sK, ws);
    k_out<true><<<gPair, blk, 0, stream>>>(Q, V, sQ, gamma, beta, ws, out);
  } else {
    k_prep<false><<<gPair, blk, 0, stream>>>(Q, K, ws, nullptr, nullptr);
    k_refq<false><<<gPair, blk, 0, stream>>>(Q, nullptr, ws);
    k_kv<false><<<gKv, blk, 0, stream>>>(K, V, nullptr, ws);
    k_out<false><<<gPair, blk, 0, stream>>>(Q, V, nullptr, gamma, beta, ws, out);
  }
}

// Round 3
// 190.773 us; speedup vs baseline: 1.4253x; 1.3454x over previous
//
#include <hip/hip_runtime.h>
#include <math.h>
#include <stdint.h>

constexpr int LL = 16384;
constexpr int NROW = 65536;          // N*L
constexpr int NPAIR = NROW * 8;      // 524288 (row,head) pairs
constexpr int PAIRS_PER_N = NPAIR / 4;  // 131072
constexpr float EPS = 1e-6f;
constexpr float LN_EPS = 1e-5f;

// ws float offsets — all stat arrays are atomically accumulated (zeroed by k_zero)
constexpr int OFF_QSUM = 0;      // [4][128]  sum_l sig(q)
constexpr int OFF_KSUM = 512;    // [4][128]  sum_s sig(k)
constexpr int OFF_QN   = 1024;   // [4][128]  sum_l q*nr
constexpr int OFF_KN   = 1536;   // [4][128]  sum_s k*nc
constexpr int OFF_SSUM = 2048;   // [4][8]    sum_s exp(ncr)
constexpr int OFF_KVU  = 2080;   // [4][8][256] unscaled weighted KV
constexpr int STATS_FLOATS = OFF_KVU + 4 * 2048;  // 10272
constexpr int FLOAT_END = 10304;                  // pad to 256-multiple
constexpr size_t MIR_Q_BYTE = (size_t)FLOAT_END * 4;
constexpr size_t MIR_ELEMS  = (size_t)NPAIR * 16;
constexpr size_t MIR_K_BYTE = MIR_Q_BYTE + MIR_ELEMS * 2;
constexpr size_t WS_FULL    = MIR_K_BYTE + MIR_ELEMS * 2;   // ~33.6 MB

__device__ __forceinline__ float sigm(float x) { return __fdividef(1.f, 1.f + __expf(-x)); }
__device__ __forceinline__ unsigned short f2bf(float f) {
  uint32_t x = __float_as_uint(f);
  return (unsigned short)((x + 0x7FFFu + ((x >> 16) & 1u)) >> 16);
}
__device__ __forceinline__ float bf2f(unsigned short u) {
  return __uint_as_float(((uint32_t)u) << 16);
}

template <bool MIR>
__device__ __forceinline__ void load_sig(const unsigned short* mir, const float* fp, int p, float* r) {
  if (MIR) {
    const uint4* p4 = reinterpret_cast<const uint4*>(mir + (size_t)p * 16);
    uint4 a = p4[0], b = p4[1];
    uint32_t w[8] = {a.x, a.y, a.z, a.w, b.x, b.y, b.z, b.w};
#pragma unroll
    for (int j = 0; j < 8; ++j) {
      r[2 * j]     = bf2f((unsigned short)(w[j] & 0xFFFFu));
      r[2 * j + 1] = bf2f((unsigned short)(w[j] >> 16));
    }
  } else {
    const float4* p4 = reinterpret_cast<const float4*>(fp + (size_t)p * 16);
#pragma unroll
    for (int j = 0; j < 4; ++j) {
      float4 a = p4[j];
      r[4 * j] = sigm(a.x); r[4 * j + 1] = sigm(a.y);
      r[4 * j + 2] = sigm(a.z); r[4 * j + 3] = sigm(a.w);
    }
  }
}
__device__ __forceinline__ void load_raw16(const float* fp, int p, float* r) {
  const float4* p4 = reinterpret_cast<const float4*>(fp + (size_t)p * 16);
#pragma unroll
  for (int j = 0; j < 4; ++j) {
    float4 a = p4[j];
    r[4 * j] = a.x; r[4 * j + 1] = a.y; r[4 * j + 2] = a.z; r[4 * j + 3] = a.w;
  }
}

// sums over the 8 lanes sharing (lane&7); every lane gets its group's sum
__device__ __forceinline__ float hred(float v) {
  v += __shfl_xor(v, 8, 64);
  v += __shfl_xor(v, 16, 64);
  v += __shfl_xor(v, 32, 64);
  return v;
}

// block-reduce 32 per-thread (h,d)-values, then one atomicAdd per thread into
// the global stat arrays (q side and k side).
__device__ __forceinline__ void stat_atomic2(float* q, float* k, float* dQ, float* dK, int tid) {
  __shared__ float w4[4][256];
  const int wave = tid >> 6, lane = tid & 63;
#pragma unroll
  for (int d = 0; d < 16; ++d) { q[d] = hred(q[d]); k[d] = hred(k[d]); }
  if (lane < 8) {
#pragma unroll
    for (int d = 0; d < 16; ++d) {
      w4[wave][lane * 16 + d] = q[d];
      w4[wave][128 + lane * 16 + d] = k[d];
    }
  }
  __syncthreads();
  const float v = w4[0][tid] + w4[1][tid] + w4[2][tid] + w4[3][tid];
  if (tid < 128) atomicAdd(dQ + tid, v);
  else atomicAdd(dK + (tid - 128), v);
}

// q-side-only variant (16 values per thread)
__device__ __forceinline__ void stat_atomic1(float* q, float* dQ, int tid) {
  __shared__ float w1[4][128];
  const int wave = tid >> 6, lane = tid & 63;
#pragma unroll
  for (int d = 0; d < 16; ++d) q[d] = hred(q[d]);
  if (lane < 8) {
#pragma unroll
    for (int d = 0; d < 16; ++d) w1[wave][lane * 16 + d] = q[d];
  }
  __syncthreads();
  if (tid < 128) atomicAdd(dQ + tid, w1[0][tid] + w1[1][tid] + w1[2][tid] + w1[3][tid]);
}

// zero the atomic accumulators (STATS_FLOATS is a multiple of 4)
__global__ __launch_bounds__(256) void k_zero(float4* ws4) {
  const int i = blockIdx.x * 256 + threadIdx.x;
  if (i < STATS_FLOATS / 4) ws4[i] = make_float4(0.f, 0.f, 0.f, 0.f);
}

// Pass 1: sigmoid, bf16 mirrors, qsum/ksum. 512 blocks x 4 chunks:
// register-accumulate across chunks, ONE atomic flush per block
// (contenders/address: 128, total atomics 131K).
template <bool MIR>
__global__ __launch_bounds__(256) void k_prep(const float* __restrict__ Q, const float* __restrict__ K,
                                              float* __restrict__ ws,
                                              unsigned short* __restrict__ sQ, unsigned short* __restrict__ sK) {
  const int tid = threadIdx.x;
  const int n = blockIdx.x >> 7;       // 128 blocks per n
  const int b = blockIdx.x & 127;
  float sq[16], sk[16];
#pragma unroll
  for (int d = 0; d < 16; ++d) { sq[d] = 0.f; sk[d] = 0.f; }
#pragma unroll
  for (int c = 0; c < 4; ++c) {
    const int p = n * PAIRS_PER_N + (b * 4 + c) * 256 + tid;
    float q[16], k[16];
    load_sig<false>(nullptr, Q, p, q);
    load_sig<false>(nullptr, K, p, k);
    if (MIR) {
      union U { unsigned short u[8]; uint4 v; };
      U a, bb;
#pragma unroll
      for (int j = 0; j < 8; ++j) { a.u[j] = f2bf(q[j]); bb.u[j] = f2bf(q[8 + j]); }
      uint4* dq = reinterpret_cast<uint4*>(sQ + (size_t)p * 16);
      dq[0] = a.v; dq[1] = bb.v;
#pragma unroll
      for (int j = 0; j < 8; ++j) { a.u[j] = f2bf(k[j]); bb.u[j] = f2bf(k[8 + j]); }
      uint4* dk = reinterpret_cast<uint4*>(sK + (size_t)p * 16);
      dk[0] = a.v; dk[1] = bb.v;
    }
#pragma unroll
    for (int d = 0; d < 16; ++d) { sq[d] += q[d]; sk[d] += k[d]; }
  }
  stat_atomic2(sq, sk, ws + OFF_QSUM + n * 128, ws + OFF_KSUM + n * 128, tid);
}

// Pass 2: qn = sum_l q*nr. 512 blocks x 4 chunks, register-accumulated.
template <bool MIR>
__global__ __launch_bounds__(256) void k_refq(const float* __restrict__ Q,
                                              const unsigned short* __restrict__ sQ,
                                              float* __restrict__ ws) {
  const int tid = threadIdx.x;
  const int n = blockIdx.x >> 7;
  const int b = blockIdx.x & 127;
  __shared__ float ksE[128];
  if (tid < 128) ksE[tid] = ws[OFF_KSUM + n * 128 + tid] + EPS;
  __syncthreads();
  const int h = tid & 7;
  float qn[16];
#pragma unroll
  for (int d = 0; d < 16; ++d) qn[d] = 0.f;
#pragma unroll
  for (int c = 0; c < 4; ++c) {
    const int p = n * PAIRS_PER_N + (b * 4 + c) * 256 + tid;
    float q[16];
    load_sig<MIR>(sQ, Q, p, q);
    float dr = 0.f;
#pragma unroll
    for (int d = 0; d < 16; ++d) dr += (q[d] + EPS) * ksE[h * 16 + d];
    const float nr = __fdividef(1.f, dr);
#pragma unroll
    for (int d = 0; d < 16; ++d) qn[d] += q[d] * nr;
  }
  stat_atomic1(qn, ws + OFF_QN + n * 128, tid);
}

// Pass 3 (fused): nc/kn, refine weight w = exp(k.qnE), ssum, weighted-KV tile.
// 256 blocks x 8 t-iters of 32 rows; register double-buffer prefetch of next
// tile's K/V hides HBM latency under the 32-row LDS loop. One atomic flush
// per block at the end (KVU contenders/address: 64, total atomics 512K).
template <bool MIR>
__global__ __launch_bounds__(256) void k_kv(const float* __restrict__ K, const float* __restrict__ V,
                                            const unsigned short* __restrict__ sK,
                                            float* __restrict__ ws) {
  const int tid = threadIdx.x;
  const int n = blockIdx.x >> 6;       // 64 blocks per n
  const int b = blockIdx.x & 63;
  constexpr int RS = 132;              // row stride: head-stride 16 (aligned wide reads), +4 pad
  __shared__ float qnE[128], qsE[128];
  __shared__ float ssb[8];
  __shared__ __align__(16) float kwL[32 * RS];
  __shared__ __align__(16) float vL[32 * RS];
  if (tid < 128) {
    qnE[tid] = ws[OFF_QN + n * 128 + tid] + EPS;
    qsE[tid] = ws[OFF_QSUM + n * 128 + tid] + EPS;
  }
  if (tid < 8) ssb[tid] = 0.f;
  __syncthreads();
  const int h = tid & 7, ri = tid >> 3, lane = tid & 63;
  const int h2 = tid >> 5;
  const int d0 = ((tid >> 2) & 7) * 2;
  const int e0 = (tid & 3) * 4;
  const int base = n * PAIRS_PER_N + b * 2048;   // 8 tiles x 256 pairs
  float acc[2][4] = {{0.f, 0.f, 0.f, 0.f}, {0.f, 0.f, 0.f, 0.f}};
  float kn[16];
#pragma unroll
  for (int d = 0; d < 16; ++d) kn[d] = 0.f;
  float kb[2][16], vb[2][16];
  load_sig<MIR>(sK, K, base + tid, kb[0]);
  load_raw16(V, base + tid, vb[0]);
#pragma unroll 2
  for (int t = 0; t < 8; ++t) {
    const int cur = t & 1, nxt = cur ^ 1;
    float* k = kb[cur];
    float* v = vb[cur];
    float dc = 0.f, ncr = 0.f;
#pragma unroll
    for (int d = 0; d < 16; ++d) {
      const float ke = k[d] + EPS;
      dc += ke * qsE[h * 16 + d];
      ncr += ke * qnE[h * 16 + d];
    }
    const float nc = __fdividef(1.f, dc);
#pragma unroll
    for (int d = 0; d < 16; ++d) kn[d] += k[d] * nc;
    const float w = __expf(ncr);   // ncr is O(1): no max-subtraction needed
    float sw = hred(w);
    if (lane < 8) atomicAdd(&ssb[lane], sw);
    const int wb = ri * RS + h * 16;
#pragma unroll
    for (int d = 0; d < 16; ++d) { kwL[wb + d] = k[d] * w; vL[wb + d] = v[d]; }
    // prefetch next tile before the barrier; loads stay in flight across it
    if (t < 7) {
      load_sig<MIR>(sK, K, base + (t + 1) * 256 + tid, kb[nxt]);
      load_raw16(V, base + (t + 1) * 256 + tid, vb[nxt]);
    }
    __syncthreads();
    const int rb0 = h2 * 16;
#pragma unroll 4
    for (int r = 0; r < 32; ++r) {
      const int rb = r * RS + rb0;
      const float2 kk = *reinterpret_cast<const float2*>(&kwL[rb + d0]);
      const float4 vv = *reinterpret_cast<const float4*>(&vL[rb + e0]);
      acc[0][0] += kk.x * vv.x; acc[0][1] += kk.x * vv.y;
      acc[0][2] += kk.x * vv.z; acc[0][3] += kk.x * vv.w;
      acc[1][0] += kk.y * vv.x; acc[1][1] += kk.y * vv.y;
      acc[1][2] += kk.y * vv.z; acc[1][3] += kk.y * vv.w;
    }
    __syncthreads();
  }
  // kn block-reduce + atomic
  stat_atomic1(kn, ws + OFF_KN + n * 128, tid);
  if (tid < 8) atomicAdd(&ws[OFF_SSUM + n * 8 + tid], ssb[tid]);
  // KV tile atomic accumulate: 8 adds/thread, 64 contributing blocks per address
  float* kv = ws + OFF_KVU + n * 2048 + h2 * 256;
#pragma unroll
  for (int j = 0; j < 4; ++j) atomicAdd(&kv[d0 * 16 + e0 + j], acc[0][j]);
#pragma unroll
  for (int j = 0; j < 4; ++j) atomicAdd(&kv[(d0 + 1) * 16 + e0 + j], acc[1][j]);
}

// Pass 4: x = q@kv * nr * nrr + v, LayerNorm, write out.
// Softmax scale L/ssum is applied while staging KV into LDS.
template <bool MIR>
__global__ __launch_bounds__(256) void k_out(const float* __restrict__ Q, const float* __restrict__ V,
                                             const unsigned short* __restrict__ sQ,
                                             const float* __restrict__ gamma, const float* __restrict__ beta,
                                             const float* __restrict__ ws, float* __restrict__ out) {
  const int tid = threadIdx.x;
  const int p = blockIdx.x * 256 + tid;
  const int n = blockIdx.x >> 9;
  __shared__ __align__(16) float kvs[8 * 260];  // pad 260 → conflict-free by h
  __shared__ float ksE[128], knE[128], gm[16], bt[16], ssE[8];
  if (tid < 8) ssE[tid] = __fdividef((float)LL, ws[OFF_SSUM + n * 8 + tid]);
  if (tid >= 8 && tid < 136) {
    const int i = tid - 8;
    ksE[i] = ws[OFF_KSUM + n * 128 + i] + EPS;
    knE[i] = ws[OFF_KN + n * 128 + i] + EPS;
  }
  if (tid >= 136 && tid < 152) gm[tid - 136] = gamma[tid - 136];
  else if (tid >= 152 && tid < 168) bt[tid - 152] = beta[tid - 152];
  __syncthreads();
  for (int i = tid; i < 2048; i += 256) {
    const int hh = i >> 8, de = i & 255;
    kvs[hh * 260 + de] = ws[OFF_KVU + n * 2048 + i] * ssE[hh];
  }
  __syncthreads();
  const int h = tid & 7;
  float q[16], v[16];
  load_sig<MIR>(sQ, Q, p, q);
  load_raw16(V, p, v);
  float dr = 0.f, drr = 0.f;
#pragma unroll
  for (int d = 0; d < 16; ++d) {
    const float qe = q[d] + EPS;
    dr += qe * ksE[h * 16 + d];
    drr += qe * knE[h * 16 + d];
  }
  const float sc = __fdividef(1.f, dr) * sigm(drr);
  float x[16];
#pragma unroll
  for (int e = 0; e < 16; ++e) x[e] = 0.f;
#pragma unroll
  for (int d = 0; d < 16; ++d) {
    const float qd = q[d];
    const float4* kr = reinterpret_cast<const float4*>(&kvs[h * 260 + d * 16]);
#pragma unroll
    for (int j = 0; j < 4; ++j) {
      float4 a = kr[j];
      x[4 * j] += qd * a.x; x[4 * j + 1] += qd * a.y;
      x[4 * j + 2] += qd * a.z; x[4 * j + 3] += qd * a.w;
    }
  }
#pragma unroll
  for (int e = 0; e < 16; ++e) x[e] = x[e] * sc + v[e];
  float mean = 0.f;
#pragma unroll
  for (int e = 0; e < 16; ++e) mean += x[e];
  mean *= (1.f / 16.f);
  float var = 0.f;
#pragma unroll
  for (int e = 0; e < 16; ++e) { const float t = x[e] - mean; var += t * t; }
  var *= (1.f / 16.f);
  const float inv = rsqrtf(var + LN_EPS);
#pragma unroll
  for (int e = 0; e < 16; ++e) x[e] = (x[e] - mean) * inv * gm[e] + bt[e];
  float4* op = reinterpret_cast<float4*>(out + (size_t)p * 16);
  op[0] = make_float4(x[0], x[1], x[2], x[3]);
  op[1] = make_float4(x[4], x[5], x[6], x[7]);
  op[2] = make_float4(x[8], x[9], x[10], x[11]);
  op[3] = make_float4(x[12], x[13], x[14], x[15]);
}

extern "C" void kernel_launch(void* const* d_in, const int* in_sizes, int n_in,
                              void* d_out, int out_size, void* d_ws, size_t ws_size,
                              hipStream_t stream) {
  const float* Q = (const float*)d_in[0];
  const float* K = (const float*)d_in[1];
  const float* V = (const float*)d_in[2];
  const float* gamma = (const float*)d_in[3];
  const float* beta = (const float*)d_in[4];
  float* ws = (float*)d_ws;
  float* out = (float*)d_out;
  unsigned short* sQ = (unsigned short*)((char*)d_ws + MIR_Q_BYTE);
  unsigned short* sK = (unsigned short*)((char*)d_ws + MIR_K_BYTE);

  const dim3 blk(256);
  const int gPrep = 512;               // 128 blocks/n x 4 chunks
  const int gKv = 256;                 // 64 blocks/n x 8 tiles
  const int gOut = NPAIR / 256;        // 2048
  const int gZero = (STATS_FLOATS / 4 + 255) / 256;  // 11

  k_zero<<<gZero, blk, 0, stream>>>(reinterpret_cast<float4*>(ws));
  if (ws_size >= WS_FULL) {
    k_prep<true><<<gPrep, blk, 0, stream>>>(Q, K, ws, sQ, sK);
    k_refq<true><<<gPrep, blk, 0, stream>>>(Q, sQ, ws);
    k_kv<true><<<gKv, blk, 0, stream>>>(K, V, sK, ws);
    k_out<true><<<gOut, blk, 0, stream>>>(Q, V, sQ, gamma, beta, ws, out);
  } else {
    k_prep<false><<<gPrep, blk, 0, stream>>>(Q, K, ws, nullptr, nullptr);
    k_refq<false><<<gPrep, blk, 0, stream>>>(Q, nullptr, ws);
    k_kv<false><<<gKv, blk, 0, stream>>>(K, V, nullptr, ws);
    k_out<false><<<gOut, blk, 0, stream>>>(Q, V, nullptr, gamma, beta, ws, out);
  }
}